// Round 1
// baseline (108.207 us; speedup 1.0000x reference)
//
#include <hip/hip_runtime.h>

typedef __bf16 bf16_t;
typedef __bf16 bf16x8 __attribute__((ext_vector_type(8)));
typedef float f32x4 __attribute__((ext_vector_type(4)));

#define GK 768   // inner K dim for every GEMM in this problem

// ---------------- workspace layout (bytes) ----------------
static constexpr size_t OFF_WT_QKV = 0;                                  // [2304][768] bf16
static constexpr size_t OFF_WT_CAR  = OFF_WT_QKV + (size_t)2304*768*2;   // [768][768] bf16
static constexpr size_t OFF_WT_PROJ = OFF_WT_CAR + (size_t)768*768*2;    // [768][768] bf16
static constexpr size_t OFF_WMEAN   = OFF_WT_PROJ + (size_t)768*768*2;   // [256][768] bf16
static constexpr size_t OFF_CAR     = OFF_WMEAN + (size_t)256*768*2;     // [256][768] f32
static constexpr size_t OFF_LN      = OFF_CAR + (size_t)256*768*4;       // [5120][768] bf16
static constexpr size_t OFF_QH      = OFF_LN + (size_t)5120*768*2;       // [2][12][2560][64] bf16
static constexpr size_t OFF_KH      = OFF_QH + (size_t)2*12*2560*64*2;
static constexpr size_t OFF_VH      = OFF_KH + (size_t)2*12*2560*64*2;
static constexpr size_t OFF_CTX     = OFF_VH + (size_t)2*12*2560*64*2;   // [2][2048][768] bf16

// ---------------- async global->LDS (16B per lane) ----------------
__device__ __forceinline__ void gload16(const bf16_t* g, bf16_t* lds_wave_base) {
  __builtin_amdgcn_global_load_lds(
      (const __attribute__((address_space(1))) unsigned int*)g,
      (__attribute__((address_space(3))) unsigned int*)lds_wave_base,
      16, 0, 0);
}

// ---------------- transpose + fp32->bf16 convert:  W[K][N] -> Wt[N][K] ----------------
__global__ __launch_bounds__(256) void transpose_kernel(const float* __restrict__ W,
                                                        bf16_t* __restrict__ Wt,
                                                        int Kdim, int Ndim) {
  __shared__ float tile[32][33];
  int kb = blockIdx.x * 32;
  int nb = blockIdx.y * 32;
  int tx = threadIdx.x & 31, ty = threadIdx.x >> 5;   // ty in 0..7
  #pragma unroll
  for (int i = 0; i < 32; i += 8)
    tile[ty + i][tx] = W[(size_t)(kb + ty + i) * Ndim + nb + tx];
  __syncthreads();
  #pragma unroll
  for (int i = 0; i < 32; i += 8)
    Wt[(size_t)(nb + ty + i) * Kdim + kb + tx] = (bf16_t)tile[tx][ty + i];
}

// ---------------- per-window mean of x -> bf16  [B*128][768] ----------------
__global__ __launch_bounds__(256) void wmean_kernel(const float* __restrict__ x,
                                                    bf16_t* __restrict__ wm) {
  int w = blockIdx.x;            // 0..255  (b*128 + window)
  int b = w >> 7, ww = w & 127;
  const float* base = x + ((size_t)b * 2048 + (size_t)ww * 16) * 768;
  for (int d = threadIdx.x; d < 768; d += 256) {
    float s = 0.f;
    #pragma unroll
    for (int i = 0; i < 16; i++) s += base[(size_t)i * 768 + d];
    wm[(size_t)w * 768 + d] = (bf16_t)(s * (1.f / 16.f));
  }
}

// ---------------- fused LayerNorm over "combined" rows -> bf16 ----------------
// row n < 2048: source = x[b][n][:], else source = car[b*128 + (n-2048)/4][:]
__global__ __launch_bounds__(256) void ln_kernel(const float* __restrict__ x,
                                                 const float* __restrict__ car,
                                                 const float* __restrict__ gamma,
                                                 const float* __restrict__ beta,
                                                 bf16_t* __restrict__ out) {
  __shared__ float red[8];
  int row = blockIdx.x;                 // 0 .. 5119
  int b = row / 2560, n = row - b * 2560;
  const float* src = (n < 2048)
      ? x + ((size_t)b * 2048 + n) * 768
      : car + ((size_t)(b * 128 + ((n - 2048) >> 2))) * 768;
  int t = threadIdx.x;
  float v0 = src[t], v1 = src[t + 256], v2 = src[t + 512];
  float s = v0 + v1 + v2;
  float q = v0 * v0 + v1 * v1 + v2 * v2;
  #pragma unroll
  for (int o = 32; o > 0; o >>= 1) { s += __shfl_down(s, o); q += __shfl_down(q, o); }
  int wv = t >> 6;
  if ((t & 63) == 0) { red[wv] = s; red[4 + wv] = q; }
  __syncthreads();
  s = red[0] + red[1] + red[2] + red[3];
  q = red[4] + red[5] + red[6] + red[7];
  float mean = s * (1.f / 768.f);
  float var  = q * (1.f / 768.f) - mean * mean;
  float rstd = rsqrtf(var + 1e-5f);
  bf16_t* o0 = out + (size_t)row * 768;
  o0[t]       = (bf16_t)((v0 - mean) * rstd * gamma[t]       + beta[t]);
  o0[t + 256] = (bf16_t)((v1 - mean) * rstd * gamma[t + 256] + beta[t + 256]);
  o0[t + 512] = (bf16_t)((v2 - mean) * rstd * gamma[t + 512] + beta[t + 512]);
}

// ---------------- bf16 MFMA GEMM:  C[M][N] = A[M][768] * Wt[N][768]^T + bias ----------------
// mode 0: fp32 out (car). mode 1: qkv epilogue -> q/k/v head layout bf16, q scaled.
// mode 2: fp32 out = d_out (proj).
__global__ __launch_bounds__(256) void gemm_kernel(const bf16_t* __restrict__ A,
                                                   const bf16_t* __restrict__ Bt,
                                                   const float* __restrict__ bias,
                                                   float* __restrict__ outF,
                                                   bf16_t* __restrict__ q_out,
                                                   bf16_t* __restrict__ k_out,
                                                   bf16_t* __restrict__ v_out,
                                                   int mode, int mBlocks) {
  __shared__ __align__(16) bf16_t As[128 * 32];
  __shared__ __align__(16) bf16_t Bs[128 * 32];

  int bm = blockIdx.x % mBlocks;
  int bn = blockIdx.x / mBlocks;
  int t = threadIdx.x;
  int wid = t >> 6, lane = t & 63;
  int wm = wid >> 1, wn = wid & 1;

  // staging coords: thread t loads 16B: tile row = t>>2, k-offset = (t&3)*8
  int sr = t >> 2;
  int sk = (t & 3) * 8;
  const bf16_t* gA = A + ((size_t)(bm * 128 + sr)) * GK + sk;
  const bf16_t* gB = Bt + ((size_t)(bn * 128 + sr)) * GK + sk;
  bf16_t* lA0 = As + wid * 512;          // issue 0: rows 0..63
  bf16_t* lA1 = As + 2048 + wid * 512;   // issue 1: rows 64..127
  bf16_t* lB0 = Bs + wid * 512;
  bf16_t* lB1 = Bs + 2048 + wid * 512;

  // fragment coords (A and Wt both [16 vecs][k-contiguous])
  int fr = lane & 15;
  int fk = (lane >> 4) * 8;

  f32x4 acc[4][4] = {};

  for (int k0 = 0; k0 < GK; k0 += 32) {
    gload16(gA + k0,            lA0);
    gload16(gA + k0 + 64 * GK,  lA1);
    gload16(gB + k0,            lB0);
    gload16(gB + k0 + 64 * GK,  lB1);
    __syncthreads();   // drains vmcnt -> staged data visible
    bf16x8 af[4], bfr[4];
    #pragma unroll
    for (int i = 0; i < 4; i++)
      af[i] = *(const bf16x8*)(As + (wm * 64 + i * 16 + fr) * 32 + fk);
    #pragma unroll
    for (int i = 0; i < 4; i++)
      bfr[i] = *(const bf16x8*)(Bs + (wn * 64 + i * 16 + fr) * 32 + fk);
    #pragma unroll
    for (int i = 0; i < 4; i++)
      #pragma unroll
      for (int j = 0; j < 4; j++)
        acc[i][j] = __builtin_amdgcn_mfma_f32_16x16x32_bf16(af[i], bfr[j], acc[i][j], 0, 0, 0);
    __syncthreads();   // all waves done reading before next stage overwrites
  }

  // epilogue: D layout col = lane&15, row = (lane>>4)*4 + reg   [verified m89/m91]
  #pragma unroll
  for (int i = 0; i < 4; i++) {
    int rbase = bm * 128 + wm * 64 + i * 16 + ((lane >> 4) << 2);
    #pragma unroll
    for (int j = 0; j < 4; j++) {
      int col = bn * 128 + wn * 64 + j * 16 + (lane & 15);
      f32x4 a = acc[i][j];
      float bcol = bias[col];
      #pragma unroll
      for (int r = 0; r < 4; r++) {
        int row = rbase + r;
        float val = a[r] + bcol;
        if (mode != 1) {
          outF[(size_t)row * GK + col] = val;   // N==768 for modes 0/2
        } else {
          int which = (col >= 1536) ? 2 : (col >= 768 ? 1 : 0);
          int d = col - which * 768;
          int h = d >> 6, hd = d & 63;
          int bb = row / 2560, n = row - bb * 2560;
          bf16_t* dst = (which == 0) ? q_out : (which == 1 ? k_out : v_out);
          float vv = (which == 0) ? val * 0.125f : val;   // fold SCALE into q
          dst[((((size_t)bb * 12 + h) * 2560 + n) << 6) + hd] = (bf16_t)vv;
        }
      }
    }
  }
}

// ---------------- sparse windowed attention: one wave per (b, w, h) ----------------
// 16 queries (window tokens), 20 keys (16 window tokens + 4 carriers of window w)
__global__ __launch_bounds__(64) void attn_kernel(const bf16_t* __restrict__ qh,
                                                  const bf16_t* __restrict__ kh,
                                                  const bf16_t* __restrict__ vh,
                                                  bf16_t* __restrict__ ctx) {
  __shared__ float Ks[20][64];
  __shared__ float Vs[20][64];
  int id = blockIdx.x;               // ((b*128 + w)*12 + h)
  int h = id % 12;
  int bw = id / 12;
  int w = bw & 127, b = bw >> 7;
  int t = threadIdx.x;
  const size_t headoff = (((size_t)b * 12 + h) * 2560) << 6;

  { // window-token K/V rows 0..15 (contiguous 16x64 block)
    int j = t >> 2, dd = (t & 3) * 16;
    size_t base = headoff + (((size_t)(w * 16 + j)) << 6) + dd;
    bf16x8 k0 = *(const bf16x8*)(kh + base);
    bf16x8 k1 = *(const bf16x8*)(kh + base + 8);
    bf16x8 u0 = *(const bf16x8*)(vh + base);
    bf16x8 u1 = *(const bf16x8*)(vh + base + 8);
    #pragma unroll
    for (int i = 0; i < 8; i++) {
      Ks[j][dd + i] = (float)k0[i]; Ks[j][dd + 8 + i] = (float)k1[i];
      Vs[j][dd + i] = (float)u0[i]; Vs[j][dd + 8 + i] = (float)u1[i];
    }
  }
  if (t < 16) { // carrier K/V rows 16..19
    int j = 16 + (t >> 2), dd = (t & 3) * 16;
    int n = 2048 + w * 4 + (t >> 2);
    size_t base = headoff + (((size_t)n) << 6) + dd;
    bf16x8 k0 = *(const bf16x8*)(kh + base);
    bf16x8 k1 = *(const bf16x8*)(kh + base + 8);
    bf16x8 u0 = *(const bf16x8*)(vh + base);
    bf16x8 u1 = *(const bf16x8*)(vh + base + 8);
    #pragma unroll
    for (int i = 0; i < 8; i++) {
      Ks[j][dd + i] = (float)k0[i]; Ks[j][dd + 8 + i] = (float)k1[i];
      Vs[j][dd + i] = (float)u0[i]; Vs[j][dd + 8 + i] = (float)u1[i];
    }
  }
  __syncthreads();

  int qi = t >> 2, c4 = t & 3, d0 = c4 * 16;
  float qreg[16];
  {
    const bf16_t* qp = qh + headoff + (((size_t)(w * 16 + qi)) << 6) + d0;
    bf16x8 q0 = *(const bf16x8*)qp;
    bf16x8 q1 = *(const bf16x8*)(qp + 8);
    #pragma unroll
    for (int i = 0; i < 8; i++) { qreg[i] = (float)q0[i]; qreg[8 + i] = (float)q1[i]; }
  }

  float pl[5];
  #pragma unroll
  for (int j = 0; j < 20; j++) {
    float s = 0.f;
    #pragma unroll
    for (int i = 0; i < 16; i++) s += qreg[i] * Ks[j][d0 + i];
    s += __shfl_xor(s, 1);
    s += __shfl_xor(s, 2);
    if ((j & 3) == c4) pl[j >> 2] = s;   // j>>2 static after unroll
  }
  float m = fmaxf(fmaxf(fmaxf(pl[0], pl[1]), fmaxf(pl[2], pl[3])), pl[4]);
  m = fmaxf(m, __shfl_xor(m, 1));
  m = fmaxf(m, __shfl_xor(m, 2));
  float sum = 0.f;
  #pragma unroll
  for (int i = 0; i < 5; i++) { pl[i] = __expf(pl[i] - m); sum += pl[i]; }
  sum += __shfl_xor(sum, 1);
  sum += __shfl_xor(sum, 2);
  float inv = 1.f / sum;

  float acc[16] = {};
  #pragma unroll
  for (int j = 0; j < 20; j++) {
    float pj = __shfl(pl[j >> 2], (qi << 2) | (j & 3));
    #pragma unroll
    for (int i = 0; i < 16; i++) acc[i] += pj * Vs[j][d0 + i];
  }

  bf16_t* cp = ctx + ((size_t)(b * 2048 + w * 16 + qi)) * 768 + h * 64 + d0;
  #pragma unroll
  for (int i = 0; i < 16; i++) cp[i] = (bf16_t)(acc[i] * inv);
}

// ---------------- launch ----------------
extern "C" void kernel_launch(void* const* d_in, const int* in_sizes, int n_in,
                              void* d_out, int out_size, void* d_ws, size_t ws_size,
                              hipStream_t stream) {
  (void)in_sizes; (void)n_in; (void)out_size; (void)ws_size;
  const float* x      = (const float*)d_in[0];
  const float* W_qkv  = (const float*)d_in[1];
  const float* b_qkv  = (const float*)d_in[2];
  const float* W_car  = (const float*)d_in[3];
  const float* b_car  = (const float*)d_in[4];
  const float* W_proj = (const float*)d_in[5];
  const float* b_proj = (const float*)d_in[6];
  const float* gamma  = (const float*)d_in[7];
  const float* beta   = (const float*)d_in[8];
  float* out = (float*)d_out;

  char* ws = (char*)d_ws;
  bf16_t* wt_qkv  = (bf16_t*)(ws + OFF_WT_QKV);
  bf16_t* wt_car  = (bf16_t*)(ws + OFF_WT_CAR);
  bf16_t* wt_proj = (bf16_t*)(ws + OFF_WT_PROJ);
  bf16_t* wmean   = (bf16_t*)(ws + OFF_WMEAN);
  float*  car_f32 = (float*) (ws + OFF_CAR);
  bf16_t* ln      = (bf16_t*)(ws + OFF_LN);
  bf16_t* q_h     = (bf16_t*)(ws + OFF_QH);
  bf16_t* k_h     = (bf16_t*)(ws + OFF_KH);
  bf16_t* v_h     = (bf16_t*)(ws + OFF_VH);
  bf16_t* ctx     = (bf16_t*)(ws + OFF_CTX);

  // 1. weights -> bf16 transposed
  transpose_kernel<<<dim3(24, 72), 256, 0, stream>>>(W_qkv,  wt_qkv,  768, 2304);
  transpose_kernel<<<dim3(24, 24), 256, 0, stream>>>(W_car,  wt_car,  768, 768);
  transpose_kernel<<<dim3(24, 24), 256, 0, stream>>>(W_proj, wt_proj, 768, 768);
  // 2. window means
  wmean_kernel<<<256, 256, 0, stream>>>(x, wmean);
  // 3. carrier tokens: car = wmean @ W_car + b_car   (fp32 out)
  gemm_kernel<<<2 * 6, 256, 0, stream>>>(wmean, wt_car, b_car, car_f32,
                                         nullptr, nullptr, nullptr, 0, 2);
  // 4. LayerNorm(combined) -> bf16
  ln_kernel<<<5120, 256, 0, stream>>>(x, car_f32, gamma, beta, ln);
  // 5. QKV projection with head-layout epilogue (q pre-scaled)
  gemm_kernel<<<40 * 18, 256, 0, stream>>>(ln, wt_qkv, b_qkv, nullptr,
                                           q_h, k_h, v_h, 1, 40);
  // 6. sparse windowed attention -> ctx bf16 [B][2048][768]
  attn_kernel<<<2 * 128 * 12, 64, 0, stream>>>(q_h, k_h, v_h, ctx);
  // 7. output projection (window rows only) -> d_out fp32
  gemm_kernel<<<32 * 6, 256, 0, stream>>>(ctx, wt_proj, b_proj, out,
                                          nullptr, nullptr, nullptr, 2, 32);
}

// Round 2
// 83.156 us; speedup vs baseline: 1.3013x; 1.3013x over previous
//
#include <hip/hip_runtime.h>

typedef __bf16 bf16_t;
typedef __bf16 bf16x8 __attribute__((ext_vector_type(8)));
typedef float f32x4 __attribute__((ext_vector_type(4)));

#define GK 768   // inner K dim for every GEMM in this problem

// ---------------- workspace layout (bytes) ----------------
static constexpr size_t OFF_WT_QKV = 0;                                  // [2304][768] bf16
static constexpr size_t OFF_WT_CAR  = OFF_WT_QKV + (size_t)2304*768*2;   // [768][768] bf16
static constexpr size_t OFF_WT_PROJ = OFF_WT_CAR + (size_t)768*768*2;    // [768][768] bf16
static constexpr size_t OFF_WMEAN   = OFF_WT_PROJ + (size_t)768*768*2;   // [256][768] bf16
static constexpr size_t OFF_CARP    = OFF_WMEAN + (size_t)256*768*2;     // [4][256][768] f32 split-K partials
static constexpr size_t OFF_LN      = OFF_CARP + (size_t)4*256*768*4;    // [5120][768] bf16
static constexpr size_t OFF_QH      = OFF_LN + (size_t)5120*768*2;       // [2][12][2560][64] bf16
static constexpr size_t OFF_KH      = OFF_QH + (size_t)2*12*2560*64*2;
static constexpr size_t OFF_VH      = OFF_KH + (size_t)2*12*2560*64*2;
static constexpr size_t OFF_CTX     = OFF_VH + (size_t)2*12*2560*64*2;   // [2][2048][768] bf16

// ---------------- async global->LDS (16B per lane) ----------------
__device__ __forceinline__ void gload16(const bf16_t* g, bf16_t* lds_wave_base) {
  __builtin_amdgcn_global_load_lds(
      (const __attribute__((address_space(1))) unsigned int*)g,
      (__attribute__((address_space(3))) unsigned int*)lds_wave_base,
      16, 0, 0);
}

// ---------------- fused prep: 3 weight transposes (fp32->bf16, W[K][N]->Wt[N][K]) + window means ----------------
__global__ __launch_bounds__(256) void prep_kernel(const float* __restrict__ W_qkv,
                                                   const float* __restrict__ W_car,
                                                   const float* __restrict__ W_proj,
                                                   const float* __restrict__ x,
                                                   bf16_t* __restrict__ wt_qkv,
                                                   bf16_t* __restrict__ wt_car,
                                                   bf16_t* __restrict__ wt_proj,
                                                   bf16_t* __restrict__ wm) {
  int bid = blockIdx.x;
  if (bid < 2880) {
    __shared__ float tile[32][33];
    const float* W; bf16_t* Wt; int Ndim, kb, nb;
    if (bid < 1728) {
      W = W_qkv; Wt = wt_qkv; Ndim = 2304; kb = (bid % 24) * 32; nb = (bid / 24) * 32;
    } else if (bid < 2304) {
      int q = bid - 1728; W = W_car; Wt = wt_car; Ndim = 768; kb = (q % 24) * 32; nb = (q / 24) * 32;
    } else {
      int q = bid - 2304; W = W_proj; Wt = wt_proj; Ndim = 768; kb = (q % 24) * 32; nb = (q / 24) * 32;
    }
    int tx = threadIdx.x & 31, ty = threadIdx.x >> 5;   // ty in 0..7
    #pragma unroll
    for (int i = 0; i < 32; i += 8)
      tile[ty + i][tx] = W[(size_t)(kb + ty + i) * Ndim + nb + tx];
    __syncthreads();
    #pragma unroll
    for (int i = 0; i < 32; i += 8)
      Wt[(size_t)(nb + ty + i) * GK + kb + tx] = (bf16_t)tile[tx][ty + i];
  } else {
    int w = bid - 2880;            // 0..255  (b*128 + window)
    int b = w >> 7, ww = w & 127;
    const float* base = x + ((size_t)b * 2048 + (size_t)ww * 16) * 768;
    for (int d = threadIdx.x; d < 768; d += 256) {
      float s = 0.f;
      #pragma unroll
      for (int i = 0; i < 16; i++) s += base[(size_t)i * 768 + d];
      wm[(size_t)w * 768 + d] = (bf16_t)(s * (1.f / 16.f));
    }
  }
}

// ---------------- 64x128-tile bf16 MFMA GEMM with optional split-K ----------------
// mode 0: car partials -> outF[kz][row][col] (no bias)
// mode 2: proj -> outF[row][col] = acc + bias
__global__ __launch_bounds__(256) void gemm64_kernel(const bf16_t* __restrict__ A,
                                                     const bf16_t* __restrict__ Bt,
                                                     const float* __restrict__ bias,
                                                     float* __restrict__ outF,
                                                     int mB, int nB, int kspan, int mode) {
  __shared__ __align__(16) bf16_t As[64 * 32];
  __shared__ __align__(16) bf16_t Bs[128 * 32];
  int bid = blockIdx.x;
  int bm = bid % mB;
  int rest = bid / mB;
  int bn = rest % nB;
  int kz = rest / nB;
  int t = threadIdx.x, wid = t >> 6, lane = t & 63;
  int wm = wid >> 1, wn = wid & 1;
  int sr = t >> 2, sk = (t & 3) * 8;
  const bf16_t* gA = A + (size_t)(bm * 64 + sr) * GK + sk;
  const bf16_t* gB = Bt + (size_t)(bn * 128 + sr) * GK + sk;
  bf16_t* lA  = As + wid * 512;
  bf16_t* lB0 = Bs + wid * 512;
  bf16_t* lB1 = Bs + 2048 + wid * 512;
  int fr = lane & 15, fk = (lane >> 4) * 8;

  f32x4 acc[2][4] = {};
  int k0 = kz * kspan, kend = k0 + kspan;
  for (; k0 < kend; k0 += 32) {
    gload16(gA + k0,           lA);
    gload16(gB + k0,           lB0);
    gload16(gB + k0 + 64 * GK, lB1);
    __syncthreads();
    bf16x8 af[2], bfr[4];
    #pragma unroll
    for (int i = 0; i < 2; i++)
      af[i] = *(const bf16x8*)(As + (wm * 32 + i * 16 + fr) * 32 + fk);
    #pragma unroll
    for (int j = 0; j < 4; j++)
      bfr[j] = *(const bf16x8*)(Bs + (wn * 64 + j * 16 + fr) * 32 + fk);
    #pragma unroll
    for (int i = 0; i < 2; i++)
      #pragma unroll
      for (int j = 0; j < 4; j++)
        acc[i][j] = __builtin_amdgcn_mfma_f32_16x16x32_bf16(af[i], bfr[j], acc[i][j], 0, 0, 0);
    __syncthreads();
  }

  #pragma unroll
  for (int i = 0; i < 2; i++) {
    int rbase = bm * 64 + wm * 32 + i * 16 + ((lane >> 4) << 2);
    #pragma unroll
    for (int j = 0; j < 4; j++) {
      int col = bn * 128 + wn * 64 + j * 16 + (lane & 15);
      f32x4 a = acc[i][j];
      float bcol = (mode == 2) ? bias[col] : 0.f;
      #pragma unroll
      for (int r = 0; r < 4; r++) {
        int row = rbase + r;
        if (mode == 0)
          outF[(size_t)kz * 196608 + (size_t)row * 768 + col] = a[r];
        else
          outF[(size_t)row * 768 + col] = a[r] + bcol;
      }
    }
  }
}

// ---------------- fused LayerNorm over "combined" rows -> bf16 ----------------
// row n < 2048: src = x[b][n][:]; else src = sum of 4 car split-K partials + b_car
__global__ __launch_bounds__(256) void ln_kernel(const float* __restrict__ x,
                                                 const float* __restrict__ carP,
                                                 const float* __restrict__ b_car,
                                                 const float* __restrict__ gamma,
                                                 const float* __restrict__ beta,
                                                 bf16_t* __restrict__ out) {
  __shared__ float red[8];
  int row = blockIdx.x;                 // 0 .. 5119
  int b = row / 2560, n = row - b * 2560;
  int t = threadIdx.x;
  float v0, v1, v2;
  if (n < 2048) {
    const float* src = x + ((size_t)b * 2048 + n) * 768;
    v0 = src[t]; v1 = src[t + 256]; v2 = src[t + 512];
  } else {
    size_t ci = (size_t)(b * 128 + ((n - 2048) >> 2)) * 768;
    const float* p0 = carP + ci;
    const float* p1 = carP + ci + 196608;
    const float* p2 = carP + ci + 2 * 196608;
    const float* p3 = carP + ci + 3 * 196608;
    v0 = p0[t]       + p1[t]       + p2[t]       + p3[t]       + b_car[t];
    v1 = p0[t + 256] + p1[t + 256] + p2[t + 256] + p3[t + 256] + b_car[t + 256];
    v2 = p0[t + 512] + p1[t + 512] + p2[t + 512] + p3[t + 512] + b_car[t + 512];
  }
  float s = v0 + v1 + v2;
  float q = v0 * v0 + v1 * v1 + v2 * v2;
  #pragma unroll
  for (int o = 32; o > 0; o >>= 1) { s += __shfl_down(s, o); q += __shfl_down(q, o); }
  int wv = t >> 6;
  if ((t & 63) == 0) { red[wv] = s; red[4 + wv] = q; }
  __syncthreads();
  s = red[0] + red[1] + red[2] + red[3];
  q = red[4] + red[5] + red[6] + red[7];
  float mean = s * (1.f / 768.f);
  float var  = q * (1.f / 768.f) - mean * mean;
  float rstd = rsqrtf(var + 1e-5f);
  bf16_t* o0 = out + (size_t)row * 768;
  o0[t]       = (bf16_t)((v0 - mean) * rstd * gamma[t]       + beta[t]);
  o0[t + 256] = (bf16_t)((v1 - mean) * rstd * gamma[t + 256] + beta[t + 256]);
  o0[t + 512] = (bf16_t)((v2 - mean) * rstd * gamma[t + 512] + beta[t + 512]);
}

// ---------------- 128x128 bf16 MFMA GEMM, QKV epilogue (unchanged, verified) ----------------
__global__ __launch_bounds__(256) void gemm_kernel(const bf16_t* __restrict__ A,
                                                   const bf16_t* __restrict__ Bt,
                                                   const float* __restrict__ bias,
                                                   bf16_t* __restrict__ q_out,
                                                   bf16_t* __restrict__ k_out,
                                                   bf16_t* __restrict__ v_out,
                                                   int mBlocks) {
  __shared__ __align__(16) bf16_t As[128 * 32];
  __shared__ __align__(16) bf16_t Bs[128 * 32];

  int bm = blockIdx.x % mBlocks;
  int bn = blockIdx.x / mBlocks;
  int t = threadIdx.x;
  int wid = t >> 6, lane = t & 63;
  int wm = wid >> 1, wn = wid & 1;

  int sr = t >> 2;
  int sk = (t & 3) * 8;
  const bf16_t* gA = A + ((size_t)(bm * 128 + sr)) * GK + sk;
  const bf16_t* gB = Bt + ((size_t)(bn * 128 + sr)) * GK + sk;
  bf16_t* lA0 = As + wid * 512;
  bf16_t* lA1 = As + 2048 + wid * 512;
  bf16_t* lB0 = Bs + wid * 512;
  bf16_t* lB1 = Bs + 2048 + wid * 512;

  int fr = lane & 15;
  int fk = (lane >> 4) * 8;

  f32x4 acc[4][4] = {};

  for (int k0 = 0; k0 < GK; k0 += 32) {
    gload16(gA + k0,            lA0);
    gload16(gA + k0 + 64 * GK,  lA1);
    gload16(gB + k0,            lB0);
    gload16(gB + k0 + 64 * GK,  lB1);
    __syncthreads();
    bf16x8 af[4], bfr[4];
    #pragma unroll
    for (int i = 0; i < 4; i++)
      af[i] = *(const bf16x8*)(As + (wm * 64 + i * 16 + fr) * 32 + fk);
    #pragma unroll
    for (int i = 0; i < 4; i++)
      bfr[i] = *(const bf16x8*)(Bs + (wn * 64 + i * 16 + fr) * 32 + fk);
    #pragma unroll
    for (int i = 0; i < 4; i++)
      #pragma unroll
      for (int j = 0; j < 4; j++)
        acc[i][j] = __builtin_amdgcn_mfma_f32_16x16x32_bf16(af[i], bfr[j], acc[i][j], 0, 0, 0);
    __syncthreads();
  }

  #pragma unroll
  for (int i = 0; i < 4; i++) {
    int rbase = bm * 128 + wm * 64 + i * 16 + ((lane >> 4) << 2);
    #pragma unroll
    for (int j = 0; j < 4; j++) {
      int col = bn * 128 + wn * 64 + j * 16 + (lane & 15);
      f32x4 a = acc[i][j];
      float bcol = bias[col];
      #pragma unroll
      for (int r = 0; r < 4; r++) {
        int row = rbase + r;
        float val = a[r] + bcol;
        int which = (col >= 1536) ? 2 : (col >= 768 ? 1 : 0);
        int d = col - which * 768;
        int h = d >> 6, hd = d & 63;
        int bb = row / 2560, n = row - bb * 2560;
        bf16_t* dst = (which == 0) ? q_out : (which == 1 ? k_out : v_out);
        float vv = (which == 0) ? val * 0.125f : val;   // fold SCALE into q
        dst[((((size_t)bb * 12 + h) * 2560 + n) << 6) + hd] = (bf16_t)vv;
      }
    }
  }
}

// ---------------- sparse windowed attention: one wave per (b, w, h) ----------------
__global__ __launch_bounds__(64) void attn_kernel(const bf16_t* __restrict__ qh,
                                                  const bf16_t* __restrict__ kh,
                                                  const bf16_t* __restrict__ vh,
                                                  bf16_t* __restrict__ ctx) {
  __shared__ float Ks[20][64];
  __shared__ float Vs[20][64];
  int id = blockIdx.x;               // ((b*128 + w)*12 + h)
  int h = id % 12;
  int bw = id / 12;
  int w = bw & 127, b = bw >> 7;
  int t = threadIdx.x;
  const size_t headoff = (((size_t)b * 12 + h) * 2560) << 6;

  {
    int j = t >> 2, dd = (t & 3) * 16;
    size_t base = headoff + (((size_t)(w * 16 + j)) << 6) + dd;
    bf16x8 k0 = *(const bf16x8*)(kh + base);
    bf16x8 k1 = *(const bf16x8*)(kh + base + 8);
    bf16x8 u0 = *(const bf16x8*)(vh + base);
    bf16x8 u1 = *(const bf16x8*)(vh + base + 8);
    #pragma unroll
    for (int i = 0; i < 8; i++) {
      Ks[j][dd + i] = (float)k0[i]; Ks[j][dd + 8 + i] = (float)k1[i];
      Vs[j][dd + i] = (float)u0[i]; Vs[j][dd + 8 + i] = (float)u1[i];
    }
  }
  if (t < 16) {
    int j = 16 + (t >> 2), dd = (t & 3) * 16;
    int n = 2048 + w * 4 + (t >> 2);
    size_t base = headoff + (((size_t)n) << 6) + dd;
    bf16x8 k0 = *(const bf16x8*)(kh + base);
    bf16x8 k1 = *(const bf16x8*)(kh + base + 8);
    bf16x8 u0 = *(const bf16x8*)(vh + base);
    bf16x8 u1 = *(const bf16x8*)(vh + base + 8);
    #pragma unroll
    for (int i = 0; i < 8; i++) {
      Ks[j][dd + i] = (float)k0[i]; Ks[j][dd + 8 + i] = (float)k1[i];
      Vs[j][dd + i] = (float)u0[i]; Vs[j][dd + 8 + i] = (float)u1[i];
    }
  }
  __syncthreads();

  int qi = t >> 2, c4 = t & 3, d0 = c4 * 16;
  float qreg[16];
  {
    const bf16_t* qp = qh + headoff + (((size_t)(w * 16 + qi)) << 6) + d0;
    bf16x8 q0 = *(const bf16x8*)qp;
    bf16x8 q1 = *(const bf16x8*)(qp + 8);
    #pragma unroll
    for (int i = 0; i < 8; i++) { qreg[i] = (float)q0[i]; qreg[8 + i] = (float)q1[i]; }
  }

  float pl[5];
  #pragma unroll
  for (int j = 0; j < 20; j++) {
    float s = 0.f;
    #pragma unroll
    for (int i = 0; i < 16; i++) s += qreg[i] * Ks[j][d0 + i];
    s += __shfl_xor(s, 1);
    s += __shfl_xor(s, 2);
    if ((j & 3) == c4) pl[j >> 2] = s;
  }
  float m = fmaxf(fmaxf(fmaxf(pl[0], pl[1]), fmaxf(pl[2], pl[3])), pl[4]);
  m = fmaxf(m, __shfl_xor(m, 1));
  m = fmaxf(m, __shfl_xor(m, 2));
  float sum = 0.f;
  #pragma unroll
  for (int i = 0; i < 5; i++) { pl[i] = __expf(pl[i] - m); sum += pl[i]; }
  sum += __shfl_xor(sum, 1);
  sum += __shfl_xor(sum, 2);
  float inv = 1.f / sum;

  float acc[16] = {};
  #pragma unroll
  for (int j = 0; j < 20; j++) {
    float pj = __shfl(pl[j >> 2], (qi << 2) | (j & 3));
    #pragma unroll
    for (int i = 0; i < 16; i++) acc[i] += pj * Vs[j][d0 + i];
  }

  bf16_t* cp = ctx + ((size_t)(b * 2048 + w * 16 + qi)) * 768 + h * 64 + d0;
  #pragma unroll
  for (int i = 0; i < 16; i++) cp[i] = (bf16_t)(acc[i] * inv);
}

// ---------------- launch ----------------
extern "C" void kernel_launch(void* const* d_in, const int* in_sizes, int n_in,
                              void* d_out, int out_size, void* d_ws, size_t ws_size,
                              hipStream_t stream) {
  (void)in_sizes; (void)n_in; (void)out_size; (void)ws_size;
  const float* x      = (const float*)d_in[0];
  const float* W_qkv  = (const float*)d_in[1];
  const float* b_qkv  = (const float*)d_in[2];
  const float* W_car  = (const float*)d_in[3];
  const float* b_car  = (const float*)d_in[4];
  const float* W_proj = (const float*)d_in[5];
  const float* b_proj = (const float*)d_in[6];
  const float* gamma  = (const float*)d_in[7];
  const float* beta   = (const float*)d_in[8];
  float* out = (float*)d_out;

  char* ws = (char*)d_ws;
  bf16_t* wt_qkv  = (bf16_t*)(ws + OFF_WT_QKV);
  bf16_t* wt_car  = (bf16_t*)(ws + OFF_WT_CAR);
  bf16_t* wt_proj = (bf16_t*)(ws + OFF_WT_PROJ);
  bf16_t* wmean   = (bf16_t*)(ws + OFF_WMEAN);
  float*  carP    = (float*) (ws + OFF_CARP);
  bf16_t* ln      = (bf16_t*)(ws + OFF_LN);
  bf16_t* q_h     = (bf16_t*)(ws + OFF_QH);
  bf16_t* k_h     = (bf16_t*)(ws + OFF_KH);
  bf16_t* v_h     = (bf16_t*)(ws + OFF_VH);
  bf16_t* ctx     = (bf16_t*)(ws + OFF_CTX);

  // 1. fused prep: weight transposes + window means
  prep_kernel<<<3136, 256, 0, stream>>>(W_qkv, W_car, W_proj, x,
                                        wt_qkv, wt_car, wt_proj, wmean);
  // 2. carrier GEMM, split-K=4 -> partials [4][256][768]
  gemm64_kernel<<<4 * 6 * 4, 256, 0, stream>>>(wmean, wt_car, nullptr, carP,
                                               4, 6, 192, 0);
  // 3. LayerNorm(combined) -> bf16  (sums car partials + b_car inline)
  ln_kernel<<<5120, 256, 0, stream>>>(x, carP, b_car, gamma, beta, ln);
  // 4. QKV projection with head-layout epilogue (q pre-scaled)
  gemm_kernel<<<40 * 18, 256, 0, stream>>>(ln, wt_qkv, b_qkv, q_h, k_h, v_h, 40);
  // 5. sparse windowed attention -> ctx bf16
  attn_kernel<<<2 * 128 * 12, 64, 0, stream>>>(q_h, k_h, v_h, ctx);
  // 6. output projection -> d_out fp32
  gemm64_kernel<<<64 * 6, 256, 0, stream>>>(ctx, wt_proj, b_proj, out,
                                            64, 6, 768, 2);
}